// Round 2
// baseline (111.443 us; speedup 1.0000x reference)
//
#include <hip/hip_runtime.h>
#include <stdint.h>

typedef unsigned short u16;
typedef unsigned int u32;
typedef unsigned long long u64;

typedef __bf16 bf16x8 __attribute__((ext_vector_type(8)));
typedef float f32x4 __attribute__((ext_vector_type(4)));

#define NQ 512
#define NC 16
#define NH 128
#define NB 2048
#define ITEMS 4
#define WSTRIDE 136   // u16 per padded row (128 data + 8 pad) -> 272 B
#define SENT (-3.0e38f)

static __device__ __forceinline__ float bf2f(u16 u){ return __uint_as_float(((u32)u)<<16); }
static __device__ __forceinline__ u16 f2bf_rne(float f){
  u32 u = __float_as_uint(f);
  u += 0x7fffu + ((u>>16)&1u);
  return (u16)(u>>16);
}
static __device__ __forceinline__ u32 pack_rne(float lo, float hi){
  return (u32)f2bf_rne(lo) | ((u32)f2bf_rne(hi)<<16);
}
// for values already exactly representable in bf16
static __device__ __forceinline__ u32 pack_trunc(float lo, float hi){
  return (__float_as_uint(lo)>>16) | (__float_as_uint(hi)&0xffff0000u);
}

union Frag { u32 u[4]; uint4 u4; bf16x8 f; };

template<bool IS_BF16>
__global__ __launch_bounds__(256, 2)
void core_snapshot_kernel(const int* __restrict__ la,
                          const void* __restrict__ adj_,
                          const void* __restrict__ qe_,
                          const void* __restrict__ gw_,
                          const void* __restrict__ gb_,
                          void* __restrict__ out_)
{
  // ---- runtime dtype detect: adjacency is all-ones ----
  // bf16: first dword = 0x3f803f80 ; fp32: 0x3f800000
  {
    u32 w0 = *(const u32*)adj_;
    bool is_bf16 = (w0 == 0x3f803f80u);
    if (is_bf16 != IS_BF16) return;   // uniform exit, nothing written
  }

  __shared__ __align__(16) u16 sW[128*WSTRIDE];   // gcn_weight as bf16, padded rows
  __shared__ __align__(16) u16 sE[16*WSTRIDE];    // core_embs as bf16
  __shared__ __align__(16) u16 sHB[128*16];       // H transposed: [o][core]
  __shared__ u16 sList[16*64];                    // per-core qubit lists
  __shared__ u32 sHist[8*16];
  __shared__ u32 sBase[8*16];
  __shared__ u32 sCnt[16];
  __shared__ float sDinv[16];

  const int tid  = threadIdx.x;
  const int lane = tid & 63;
  const int wv   = tid >> 6;
  const int m    = lane & 15;
  const int quad = lane >> 4;

  auto ldin = [&](const void* p, int i) -> float {
    if constexpr (IS_BF16) return bf2f(((const u16*)p)[i]);
    else                   return ((const float*)p)[i];
  };

  // ---- stage W into LDS as bf16 (once per block) ----
  if constexpr (IS_BF16) {
    const uint4* wg = (const uint4*)gw_;   // 128x128 bf16 = 2048 uint4
    #pragma unroll
    for (int i = 0; i < 8; ++i) {
      int idx = tid + i*256;
      uint4 v = wg[idx];
      int row = idx >> 4, col8 = (idx & 15) << 3;
      *(uint4*)&sW[row*WSTRIDE + col8] = v;
    }
  } else {
    const float4* wg = (const float4*)gw_;  // 128x128 f32 = 4096 float4
    #pragma unroll
    for (int i = 0; i < 16; ++i) {
      int idx = tid + i*256;
      float4 v = wg[idx];
      int row = idx >> 5, col4 = (idx & 31) << 2;
      uint2 p; p.x = pack_rne(v.x, v.y); p.y = pack_rne(v.z, v.w);
      *(uint2*)&sW[row*WSTRIDE + col4] = p;
    }
  }
  // ---- dinv from adjacency column sums ----
  if (tid < 16) {
    float s = 0.f;
    for (int i = 0; i < 16; ++i) s += ldin(adj_, i*16 + tid);
    sDinv[tid] = (s > 0.f) ? (1.0f / sqrtf(s)) : 0.f;
  }
  __syncthreads();

  // ---- A_norm MFMA A-fragment (K padded 16->32 with zeros; constant across items) ----
  Frag afr2;
  #pragma unroll
  for (int jj = 0; jj < 4; ++jj) {
    float lo = 0.f, hi = 0.f;
    if (quad < 2) {
      int k0 = quad*8 + jj*2;   // 0..15
      lo = ldin(adj_, m*16 + k0)     * sDinv[m] * sDinv[k0];
      hi = ldin(adj_, m*16 + k0 + 1) * sDinv[m] * sDinv[k0 + 1];
    }
    afr2.u[jj] = pack_rne(lo, hi);
  }
  // ---- bias for this thread's two 16-col tiles ----
  float biasv[2];
  #pragma unroll
  for (int t = 0; t < 2; ++t) biasv[t] = ldin(gb_, (wv*2 + t)*16 + m);

  const u64 lmask = (1ull << lane) - 1ull;

  for (int it = 0; it < ITEMS; ++it) {
    const int b = blockIdx.x * ITEMS + it;

    // ---- phase 1: ranks via wave ballots (chunk = q/64 preserves qubit order) ----
    int av[2]; u32 intra[2];
    #pragma unroll
    for (int r = 0; r < 2; ++r) {
      int ch = wv*2 + r;
      av[r] = la[b*NQ + ch*64 + lane];
    }
    __syncthreads();   // previous item done reading sList/sHB/sE
    #pragma unroll
    for (int r = 0; r < 2; ++r) {
      int ch = wv*2 + r;
      for (int c = 0; c < 16; ++c) {
        u64 mk = __ballot(av[r] == c);
        if (lane == c)  sHist[ch*16 + c] = (u32)__popcll(mk);
        if (av[r] == c) intra[r] = (u32)__popcll(mk & lmask);
      }
    }
    __syncthreads();
    if (tid < 16) {
      u32 run = 0;
      for (int ch = 0; ch < 8; ++ch) { sBase[ch*16 + tid] = run; run += sHist[ch*16 + tid]; }
      sCnt[tid] = run;
    }
    __syncthreads();
    #pragma unroll
    for (int r = 0; r < 2; ++r) {
      int ch = wv*2 + r;
      u32 rank = sBase[ch*16 + av[r]] + intra[r];
      if (rank < 64) sList[av[r]*64 + rank] = (u16)(ch*64 + lane);  // first-64 drop semantics
    }
    __syncthreads();

    // ---- phase 2: gather + per-core max -> sE (bf16) ----
    {
      const int s0 = quad;   // slot subgroup (4 qubits processed per step)
      const int d  = m;      // dim chunk: 8 dims of 128
      for (int cc = 0; cc < 4; ++cc) {
        int c = wv*4 + cc;
        int cntc = (int)min(sCnt[c], 64u);
        float a0=SENT,a1=SENT,a2=SENT,a3=SENT,a4=SENT,a5=SENT,a6=SENT,a7=SENT;
        int iters = (cntc + 3) >> 2;
        for (int k = 0; k < iters; ++k) {
          int slot = k*4 + s0;
          bool valid = slot < cntc;
          int qv = valid ? (int)sList[c*64 + slot] : 0;
          float v0,v1,v2,v3,v4,v5,v6,v7;
          if constexpr (IS_BF16) {
            uint4 tt = *(const uint4*)((const u16*)qe_ + qv*NH + d*8);
            v0 = __uint_as_float(tt.x << 16); v1 = __uint_as_float(tt.x & 0xffff0000u);
            v2 = __uint_as_float(tt.y << 16); v3 = __uint_as_float(tt.y & 0xffff0000u);
            v4 = __uint_as_float(tt.z << 16); v5 = __uint_as_float(tt.z & 0xffff0000u);
            v6 = __uint_as_float(tt.w << 16); v7 = __uint_as_float(tt.w & 0xffff0000u);
          } else {
            const float4* pp = (const float4*)((const float*)qe_ + qv*NH + d*8);
            float4 t0 = pp[0], t1 = pp[1];
            v0=t0.x; v1=t0.y; v2=t0.z; v3=t0.w; v4=t1.x; v5=t1.y; v6=t1.z; v7=t1.w;
          }
          if (!valid) { v0=SENT; v1=SENT; v2=SENT; v3=SENT; v4=SENT; v5=SENT; v6=SENT; v7=SENT; }
          a0 = fmaxf(a0, v0); a1 = fmaxf(a1, v1); a2 = fmaxf(a2, v2); a3 = fmaxf(a3, v3);
          a4 = fmaxf(a4, v4); a5 = fmaxf(a5, v5); a6 = fmaxf(a6, v6); a7 = fmaxf(a7, v7);
        }
        // reduce over the 4 slot subgroups (lanes l, l^16, l^32)
        a0 = fmaxf(a0, __shfl_xor(a0, 16)); a0 = fmaxf(a0, __shfl_xor(a0, 32));
        a1 = fmaxf(a1, __shfl_xor(a1, 16)); a1 = fmaxf(a1, __shfl_xor(a1, 32));
        a2 = fmaxf(a2, __shfl_xor(a2, 16)); a2 = fmaxf(a2, __shfl_xor(a2, 32));
        a3 = fmaxf(a3, __shfl_xor(a3, 16)); a3 = fmaxf(a3, __shfl_xor(a3, 32));
        a4 = fmaxf(a4, __shfl_xor(a4, 16)); a4 = fmaxf(a4, __shfl_xor(a4, 32));
        a5 = fmaxf(a5, __shfl_xor(a5, 16)); a5 = fmaxf(a5, __shfl_xor(a5, 32));
        a6 = fmaxf(a6, __shfl_xor(a6, 16)); a6 = fmaxf(a6, __shfl_xor(a6, 32));
        a7 = fmaxf(a7, __shfl_xor(a7, 16)); a7 = fmaxf(a7, __shfl_xor(a7, 32));
        if (cntc < 64) {   // padding slots hit zeroed embedding row 512
          a0=fmaxf(a0,0.f); a1=fmaxf(a1,0.f); a2=fmaxf(a2,0.f); a3=fmaxf(a3,0.f);
          a4=fmaxf(a4,0.f); a5=fmaxf(a5,0.f); a6=fmaxf(a6,0.f); a7=fmaxf(a7,0.f);
        }
        if (quad == 0) {
          uint4 e;
          if constexpr (IS_BF16) {  // maxes of bf16 values are exact bf16
            e.x = pack_trunc(a0,a1); e.y = pack_trunc(a2,a3);
            e.z = pack_trunc(a4,a5); e.w = pack_trunc(a6,a7);
          } else {
            e.x = pack_rne(a0,a1); e.y = pack_rne(a2,a3);
            e.z = pack_rne(a4,a5); e.w = pack_rne(a6,a7);
          }
          *(uint4*)&sE[c*WSTRIDE + d*8] = e;
        }
      }
    }
    __syncthreads();

    // ---- phase 3: H = E @ W^T via MFMA -> sHB[o][core] (bf16) ----
    {
      bf16x8 af[4];
      #pragma unroll
      for (int ks = 0; ks < 4; ++ks)
        af[ks] = *(const bf16x8*)&sE[m*WSTRIDE + ks*32 + quad*8];
      #pragma unroll
      for (int t = 0; t < 2; ++t) {
        int o = (wv*2 + t)*16 + m;
        f32x4 acc = {0.f, 0.f, 0.f, 0.f};
        #pragma unroll
        for (int ks = 0; ks < 4; ++ks) {
          bf16x8 bfr = *(const bf16x8*)&sW[o*WSTRIDE + ks*32 + quad*8];
          acc = __builtin_amdgcn_mfma_f32_16x16x32_bf16(af[ks], bfr, acc, 0, 0, 0);
        }
        // C/D layout: col=lane&15 (o within tile), row=quad*4+reg (core)
        *(u32*)&sHB[o*16 + quad*4]     = pack_rne(acc[0], acc[1]);
        *(u32*)&sHB[o*16 + quad*4 + 2] = pack_rne(acc[2], acc[3]);
      }
    }
    __syncthreads();

    // ---- phase 4: out = A_norm @ H + bias (K padded 16->32) ----
    #pragma unroll
    for (int t = 0; t < 2; ++t) {
      int o = (wv*2 + t)*16 + m;
      Frag bfr;
      if (quad < 2) bfr.u4 = *(const uint4*)&sHB[o*16 + quad*8];
      else { bfr.u[0]=0; bfr.u[1]=0; bfr.u[2]=0; bfr.u[3]=0; }
      f32x4 acc = {biasv[t], biasv[t], biasv[t], biasv[t]};
      acc = __builtin_amdgcn_mfma_f32_16x16x32_bf16(afr2.f, bfr.f, acc, 0, 0, 0);
      if constexpr (IS_BF16) {
        u16* op = (u16*)out_ + b*(NC*NH) + o;
        #pragma unroll
        for (int r = 0; r < 4; ++r) op[(quad*4 + r)*NH] = f2bf_rne(acc[r]);
      } else {
        float* op = (float*)out_ + b*(NC*NH) + o;
        #pragma unroll
        for (int r = 0; r < 4; ++r) op[(quad*4 + r)*NH] = acc[r];
      }
    }
  }
}

extern "C" void kernel_launch(void* const* d_in, const int* in_sizes, int n_in,
                              void* d_out, int out_size, void* d_ws, size_t ws_size,
                              hipStream_t stream) {
  const int* la   = (const int*)d_in[0];   // (2048, 512) int32
  const void* adj = d_in[1];               // (16,16)
  const void* qe  = d_in[2];               // (513,128)
  const void* gw  = d_in[3];               // (128,128)
  const void* gb  = d_in[4];               // (128,)
  // Dtype of float tensors (bf16 vs fp32) detected on-device from adjacency
  // (all-ones): each instantiation early-exits if the data isn't its dtype.
  core_snapshot_kernel<true ><<<NB/ITEMS, 256, 0, stream>>>(la, adj, qe, gw, gb, d_out);
  core_snapshot_kernel<false><<<NB/ITEMS, 256, 0, stream>>>(la, adj, qe, gw, gb, d_out);
}

// Round 3
// 106.971 us; speedup vs baseline: 1.0418x; 1.0418x over previous
//
#include <hip/hip_runtime.h>
#include <stdint.h>

typedef unsigned short u16;
typedef unsigned int u32;
typedef unsigned long long u64;

typedef __bf16 bf16x8 __attribute__((ext_vector_type(8)));
typedef float f32x4 __attribute__((ext_vector_type(4)));

#define NQ 512
#define NC 16
#define NH 128
#define NB 2048
#define ITEMS 2        // 1024 blocks = exactly 4 blocks/CU
#define ESTRIDE 136    // sE row stride in u16
#define HSTRIDE 24     // sHB row stride in u16 (48 B: 16B-aligned, 2-way banks = free)
#define SENT (-3.0e38f)
#define QE_ELEMS (513*128)

static __device__ __forceinline__ u16 f2bf_rne(float f){
  u32 u = __float_as_uint(f);
  u += 0x7fffu + ((u>>16)&1u);
  return (u16)(u>>16);
}
static __device__ __forceinline__ u32 pack_rne(float lo, float hi){
  return (u32)f2bf_rne(lo) | ((u32)f2bf_rne(hi)<<16);
}
// for values already exactly representable in bf16 (maxes of bf16 values)
static __device__ __forceinline__ u32 pack_trunc(float lo, float hi){
  return (__float_as_uint(lo)>>16) | (__float_as_uint(hi)&0xffff0000u);
}

union Frag { u32 u[4]; uint4 u4; bf16x8 f; };

// ---- prepass: fp32 qubit_embedding -> bf16 table in d_ws ----
__global__ void qe_to_bf16_kernel(const float* __restrict__ qe, u16* __restrict__ wsq)
{
  int i8 = (blockIdx.x * 256 + threadIdx.x) * 8;
  if (i8 + 8 > QE_ELEMS) return;
  const float4* p = (const float4*)(qe + i8);
  float4 a = p[0], b = p[1];
  uint4 o;
  o.x = pack_rne(a.x, a.y); o.y = pack_rne(a.z, a.w);
  o.z = pack_rne(b.x, b.y); o.w = pack_rne(b.z, b.w);
  *(uint4*)(wsq + i8) = o;
}

__global__ __launch_bounds__(256, 4)
void core_snapshot_kernel(const int* __restrict__ la,
                          const float* __restrict__ adj,
                          const u16* __restrict__ qt,    // bf16 table (d_ws)
                          const float* __restrict__ gw,
                          const float* __restrict__ gb,
                          float* __restrict__ outp)
{
  __shared__ __align__(16) u16 sE[16*ESTRIDE];    // core_embs (bf16, exact)
  __shared__ __align__(16) u16 sHB[128*HSTRIDE];  // H transposed: [o][core]
  __shared__ u16 sList[16*64];                    // per-core qubit lists
  __shared__ u32 sHist[8*16];
  __shared__ u32 sBase[8*16];
  __shared__ u32 sCnt[16];
  __shared__ float sDinv[16];

  const int tid  = threadIdx.x;
  const int lane = tid & 63;
  const int wv   = tid >> 6;
  const int m    = lane & 15;
  const int quad = lane >> 4;

  // ---- W B-fragments into registers (once per block, from L2) ----
  // phase-3 needs B[k=h][n=o] = W[o][h]; this thread's o = (wv*2+t)*16+m,
  // k-slice for step ks: h = ks*32 + quad*8 + j, j=0..7
  Frag wfr[2][4];
  #pragma unroll
  for (int t = 0; t < 2; ++t) {
    int o = (wv*2 + t)*16 + m;
    #pragma unroll
    for (int ks = 0; ks < 4; ++ks) {
      const float4* p = (const float4*)(gw + o*NH + ks*32 + quad*8);
      float4 x = p[0], y = p[1];
      wfr[t][ks].u[0] = pack_rne(x.x, x.y);
      wfr[t][ks].u[1] = pack_rne(x.z, x.w);
      wfr[t][ks].u[2] = pack_rne(y.x, y.y);
      wfr[t][ks].u[3] = pack_rne(y.z, y.w);
    }
  }
  // ---- dinv from adjacency column sums ----
  if (tid < 16) {
    float s = 0.f;
    for (int i = 0; i < 16; ++i) s += adj[i*16 + tid];
    sDinv[tid] = (s > 0.f) ? (1.0f / sqrtf(s)) : 0.f;
  }
  __syncthreads();

  // ---- A_norm MFMA A-fragment (K padded 16->32 with zeros) ----
  Frag afr2;
  #pragma unroll
  for (int jj = 0; jj < 4; ++jj) {
    float lo = 0.f, hi = 0.f;
    if (quad < 2) {
      int k0 = quad*8 + jj*2;   // 0..15
      lo = adj[m*16 + k0]     * sDinv[m] * sDinv[k0];
      hi = adj[m*16 + k0 + 1] * sDinv[m] * sDinv[k0 + 1];
    }
    afr2.u[jj] = pack_rne(lo, hi);
  }
  // ---- bias for this thread's two 16-col tiles ----
  float biasv[2];
  #pragma unroll
  for (int t = 0; t < 2; ++t) biasv[t] = gb[(wv*2 + t)*16 + m];

  const u64 lmask = (1ull << lane) - 1ull;

  for (int it = 0; it < ITEMS; ++it) {
    const int b = blockIdx.x * ITEMS + it;

    // ---- phase 1: ranks via wave ballots (chunk = q/64 preserves qubit order) ----
    int av[2]; u32 intra[2];
    #pragma unroll
    for (int r = 0; r < 2; ++r) {
      int ch = wv*2 + r;
      av[r] = la[b*NQ + ch*64 + lane];
    }
    __syncthreads();   // previous item done with sList/sHB/sE
    #pragma unroll
    for (int r = 0; r < 2; ++r) {
      int ch = wv*2 + r;
      #pragma unroll
      for (int c = 0; c < 16; ++c) {
        u64 mk = __ballot(av[r] == c);
        if (lane == c)  sHist[ch*16 + c] = (u32)__popcll(mk);
        if (av[r] == c) intra[r] = (u32)__popcll(mk & lmask);
      }
    }
    __syncthreads();
    if (tid < 16) {
      u32 run = 0;
      #pragma unroll
      for (int ch = 0; ch < 8; ++ch) { sBase[ch*16 + tid] = run; run += sHist[ch*16 + tid]; }
      sCnt[tid] = run;
    }
    __syncthreads();
    #pragma unroll
    for (int r = 0; r < 2; ++r) {
      int ch = wv*2 + r;
      u32 rank = sBase[ch*16 + av[r]] + intra[r];
      if (rank < 64) sList[av[r]*64 + rank] = (u16)(ch*64 + lane);  // first-64 drop
    }
    __syncthreads();

    // ---- phase 2: gather (bf16 table) + per-core max -> sE ----
    {
      const int s0 = quad;   // slot subgroup: 4 qubits per step
      const int d  = m;      // dim chunk: 8 of 128
      for (int cc = 0; cc < 4; ++cc) {
        int c = wv*4 + cc;
        int cntc = (int)min(sCnt[c], 64u);
        float a0=SENT,a1=SENT,a2=SENT,a3=SENT,a4=SENT,a5=SENT,a6=SENT,a7=SENT;
        int iters = (cntc + 3) >> 2;
        for (int k = 0; k < iters; ++k) {
          int slot = k*4 + s0;
          bool valid = slot < cntc;
          int qv = valid ? (int)sList[c*64 + slot] : 0;
          uint4 tt = *(const uint4*)(qt + qv*NH + d*8);
          if (!valid) { tt.x = 0xff80ff80u; tt.y = 0xff80ff80u; tt.z = 0xff80ff80u; tt.w = 0xff80ff80u; }
          a0 = fmaxf(a0, __uint_as_float(tt.x << 16));
          a1 = fmaxf(a1, __uint_as_float(tt.x & 0xffff0000u));
          a2 = fmaxf(a2, __uint_as_float(tt.y << 16));
          a3 = fmaxf(a3, __uint_as_float(tt.y & 0xffff0000u));
          a4 = fmaxf(a4, __uint_as_float(tt.z << 16));
          a5 = fmaxf(a5, __uint_as_float(tt.z & 0xffff0000u));
          a6 = fmaxf(a6, __uint_as_float(tt.w << 16));
          a7 = fmaxf(a7, __uint_as_float(tt.w & 0xffff0000u));
        }
        a0 = fmaxf(a0, __shfl_xor(a0, 16)); a0 = fmaxf(a0, __shfl_xor(a0, 32));
        a1 = fmaxf(a1, __shfl_xor(a1, 16)); a1 = fmaxf(a1, __shfl_xor(a1, 32));
        a2 = fmaxf(a2, __shfl_xor(a2, 16)); a2 = fmaxf(a2, __shfl_xor(a2, 32));
        a3 = fmaxf(a3, __shfl_xor(a3, 16)); a3 = fmaxf(a3, __shfl_xor(a3, 32));
        a4 = fmaxf(a4, __shfl_xor(a4, 16)); a4 = fmaxf(a4, __shfl_xor(a4, 32));
        a5 = fmaxf(a5, __shfl_xor(a5, 16)); a5 = fmaxf(a5, __shfl_xor(a5, 32));
        a6 = fmaxf(a6, __shfl_xor(a6, 16)); a6 = fmaxf(a6, __shfl_xor(a6, 32));
        a7 = fmaxf(a7, __shfl_xor(a7, 16)); a7 = fmaxf(a7, __shfl_xor(a7, 32));
        if (cntc < 64) {   // padding slots hit zeroed row 512
          a0=fmaxf(a0,0.f); a1=fmaxf(a1,0.f); a2=fmaxf(a2,0.f); a3=fmaxf(a3,0.f);
          a4=fmaxf(a4,0.f); a5=fmaxf(a5,0.f); a6=fmaxf(a6,0.f); a7=fmaxf(a7,0.f);
        }
        if (quad == 0) {   // maxes of bf16 values are exact bf16 -> trunc pack
          uint4 e;
          e.x = pack_trunc(a0,a1); e.y = pack_trunc(a2,a3);
          e.z = pack_trunc(a4,a5); e.w = pack_trunc(a6,a7);
          *(uint4*)&sE[c*ESTRIDE + d*8] = e;
        }
      }
    }
    __syncthreads();

    // ---- phase 3: H = E @ W^T via MFMA -> sHB[o][core] (bf16) ----
    {
      bf16x8 af[4];
      #pragma unroll
      for (int ks = 0; ks < 4; ++ks)
        af[ks] = *(const bf16x8*)&sE[m*ESTRIDE + ks*32 + quad*8];
      #pragma unroll
      for (int t = 0; t < 2; ++t) {
        int o = (wv*2 + t)*16 + m;
        f32x4 acc = {0.f, 0.f, 0.f, 0.f};
        #pragma unroll
        for (int ks = 0; ks < 4; ++ks)
          acc = __builtin_amdgcn_mfma_f32_16x16x32_bf16(af[ks], wfr[t][ks].f, acc, 0, 0, 0);
        // C/D layout: col=lane&15 (o in tile), row=quad*4+reg (core)
        *(u32*)&sHB[o*HSTRIDE + quad*4]     = pack_rne(acc[0], acc[1]);
        *(u32*)&sHB[o*HSTRIDE + quad*4 + 2] = pack_rne(acc[2], acc[3]);
      }
    }
    __syncthreads();

    // ---- phase 4: out = A_norm @ H + bias (K padded 16->32) ----
    #pragma unroll
    for (int t = 0; t < 2; ++t) {
      int o = (wv*2 + t)*16 + m;
      Frag bfr;
      if (quad < 2) bfr.u4 = *(const uint4*)&sHB[o*HSTRIDE + quad*8];
      else { bfr.u[0]=0; bfr.u[1]=0; bfr.u[2]=0; bfr.u[3]=0; }
      f32x4 acc = {biasv[t], biasv[t], biasv[t], biasv[t]};
      acc = __builtin_amdgcn_mfma_f32_16x16x32_bf16(afr2.f, bfr.f, acc, 0, 0, 0);
      float* op = outp + b*(NC*NH) + o;
      #pragma unroll
      for (int r = 0; r < 4; ++r) op[(quad*4 + r)*NH] = acc[r];
    }
  }
}

extern "C" void kernel_launch(void* const* d_in, const int* in_sizes, int n_in,
                              void* d_out, int out_size, void* d_ws, size_t ws_size,
                              hipStream_t stream) {
  const int*   la  = (const int*)d_in[0];    // (2048, 512) int32
  const float* adj = (const float*)d_in[1];  // (16,16) fp32
  const float* qe  = (const float*)d_in[2];  // (513,128) fp32
  const float* gw  = (const float*)d_in[3];  // (128,128) fp32
  const float* gb  = (const float*)d_in[4];  // (128,) fp32
  float* outp = (float*)d_out;               // (2048,16,128) fp32
  u16* wsq = (u16*)d_ws;                     // bf16 table, 131328 B

  qe_to_bf16_kernel<<<(QE_ELEMS/8 + 255)/256, 256, 0, stream>>>(qe, wsq);
  core_snapshot_kernel<<<NB/ITEMS, 256, 0, stream>>>(la, adj, wsq, gw, gb, outp);
}

// Round 4
// 93.922 us; speedup vs baseline: 1.1865x; 1.1389x over previous
//
#include <hip/hip_runtime.h>
#include <stdint.h>

typedef unsigned short u16;
typedef unsigned int u32;
typedef unsigned long long u64;

typedef __bf16 bf16x8 __attribute__((ext_vector_type(8)));
typedef float f32x4 __attribute__((ext_vector_type(4)));
typedef u16 u16x8 __attribute__((ext_vector_type(8)));

#define NQ 512
#define NC 16
#define NH 128
#define NB 2048
#define ESTRIDE 136    // sE row stride in u16
#define HSTRIDE 24     // sHB row stride in u16
#define QE_KEYS (513*128)   // 65664 u16 keys
#define WT_OFF  QE_KEYS     // u16 offset of bf16 W copy in d_ws
#define GW_ELEMS (128*128)

static __device__ __forceinline__ u16 f2bf_rne(float f){
  u32 u = __float_as_uint(f);
  u += 0x7fffu + ((u>>16)&1u);
  return (u16)(u>>16);
}
static __device__ __forceinline__ u32 pack_rne(float lo, float hi){
  return (u32)f2bf_rne(lo) | ((u32)f2bf_rne(hi)<<16);
}
// monotone key: unsigned compare on keys == float compare on bf16 values
static __device__ __forceinline__ u16 key_of(float f){
  u16 b = f2bf_rne(f);
  return (b & 0x8000u) ? (u16)~b : (u16)(b | 0x8000u);
}
static __device__ __forceinline__ u16 unkey(u16 k){
  return (k & 0x8000u) ? (u16)(k ^ 0x8000u) : (u16)~k;
}

union Frag { u32 u[4]; uint4 u4; bf16x8 f; };
union U8   { u16x8 v; int w[4]; uint4 u4; u16 h[8]; };

// ---- prepass: qe fp32 -> u16 keys (row 512 forced to key(0)=0x8000); gw fp32 -> bf16 ----
__global__ void prepass_kernel(const float* __restrict__ qe,
                               const float* __restrict__ gw,
                               u16* __restrict__ ws)
{
  int idx = blockIdx.x * 256 + threadIdx.x;
  if (idx < QE_KEYS/8) {                       // 8208 threads: key table
    int i8 = idx * 8;
    uint4 o;
    if (i8 >= 512*NH) {                        // row 512: key of +0.0
      o.x = 0x80008000u; o.y = 0x80008000u; o.z = 0x80008000u; o.w = 0x80008000u;
    } else {
      const float4* p = (const float4*)(qe + i8);
      float4 a = p[0], b = p[1];
      o.x = (u32)key_of(a.x) | ((u32)key_of(a.y)<<16);
      o.y = (u32)key_of(a.z) | ((u32)key_of(a.w)<<16);
      o.z = (u32)key_of(b.x) | ((u32)key_of(b.y)<<16);
      o.w = (u32)key_of(b.z) | ((u32)key_of(b.w)<<16);
    }
    *(uint4*)(ws + i8) = o;
  } else if (idx < QE_KEYS/8 + GW_ELEMS/8) {   // 2048 threads: W -> bf16
    int j8 = (idx - QE_KEYS/8) * 8;
    const float4* p = (const float4*)(gw + j8);
    float4 a = p[0], b = p[1];
    uint4 o;
    o.x = pack_rne(a.x, a.y); o.y = pack_rne(a.z, a.w);
    o.z = pack_rne(b.x, b.y); o.w = pack_rne(b.z, b.w);
    *(uint4*)(ws + WT_OFF + j8) = o;
  }
}

__global__ __launch_bounds__(256, 8)
void core_snapshot_kernel(const int* __restrict__ la,
                          const float* __restrict__ adj,
                          const u16* __restrict__ ws,   // keys + bf16 W
                          const float* __restrict__ gb,
                          float* __restrict__ outp)
{
  __shared__ __align__(16) u16 sE[16*ESTRIDE];    // core_embs (bf16)
  __shared__ __align__(16) u16 sHB[128*HSTRIDE];  // H transposed: [o][core]
  __shared__ u16 sList[16*64];
  __shared__ u32 sHist[8*16];
  __shared__ u32 sBase[8*16];
  __shared__ u32 sCnt[16];
  __shared__ float sDinv[16];

  const int tid  = threadIdx.x;
  const int lane = tid & 63;
  const int wv   = tid >> 6;
  const int m    = lane & 15;
  const int quad = lane >> 4;
  const int b    = blockIdx.x;
  const u16* qt  = ws;              // key table
  const u16* wt  = ws + WT_OFF;     // bf16 W, row-major [o][h]

  // ---- phase 1: assignments + per-chunk histograms via ballots ----
  int av[2]; u32 intra[2];
  const u64 lmask = (1ull << lane) - 1ull;
  #pragma unroll
  for (int r = 0; r < 2; ++r) {
    int ch = wv*2 + r;
    av[r] = la[b*NQ + ch*64 + lane];
  }
  #pragma unroll
  for (int r = 0; r < 2; ++r) {
    int ch = wv*2 + r;
    #pragma unroll
    for (int c = 0; c < 16; ++c) {
      u64 mk = __ballot(av[r] == c);
      if (lane == c)  sHist[ch*16 + c] = (u32)__popcll(mk);
      if (av[r] == c) intra[r] = (u32)__popcll(mk & lmask);
    }
  }
  if (tid < 16) {   // dinv from adjacency column sums
    float s = 0.f;
    for (int i = 0; i < 16; ++i) s += adj[i*16 + tid];
    sDinv[tid] = (s > 0.f) ? (1.0f / sqrtf(s)) : 0.f;
  }
  __syncthreads();
  if (tid < 16) {   // exclusive prefix over chunks
    u32 run = 0;
    #pragma unroll
    for (int ch = 0; ch < 8; ++ch) { sBase[ch*16 + tid] = run; run += sHist[ch*16 + tid]; }
    sCnt[tid] = run;
  }
  __syncthreads();
  #pragma unroll
  for (int r = 0; r < 2; ++r) {
    int ch = wv*2 + r;
    u32 rank = sBase[ch*16 + av[r]] + intra[r];
    if (rank < 64) sList[av[r]*64 + rank] = (u16)(ch*64 + lane);  // first-64 drop
  }
  __syncthreads();

  // ---- phase 2: key gather + packed-u16 max -> sE (bf16) ----
  for (int cc = 0; cc < 4; ++cc) {
    int c = wv*4 + cc;               // wave-uniform core
    int cntc = (int)min(sCnt[c], 64u);
    U8 A; A.v = (u16x8)0;            // key 0 < all real-value keys
    int iters = (cntc + 3) >> 2;     // quad = slot subgroup, m = dim chunk
    for (int k = 0; k < iters; ++k) {
      int slot = k*4 + quad;
      int qv = (slot < cntc) ? (int)sList[c*64 + slot] : 512;  // row 512 = key(+0)
      U8 T; T.u4 = *(const uint4*)(qt + qv*NH + m*8);
      A.v = __builtin_elementwise_max(A.v, T.v);
    }
    // reduce over the 4 slot subgroups (lanes l ^16, ^32)
    U8 Bv;
    #pragma unroll
    for (int j = 0; j < 4; ++j) Bv.w[j] = __shfl_xor(A.w[j], 16);
    A.v = __builtin_elementwise_max(A.v, Bv.v);
    #pragma unroll
    for (int j = 0; j < 4; ++j) Bv.w[j] = __shfl_xor(A.w[j], 32);
    A.v = __builtin_elementwise_max(A.v, Bv.v);
    if (cntc < 64) {                 // padding slots contribute +0 (relu)
      U8 Z; Z.v = (u16x8)(u16)0x8000u;
      A.v = __builtin_elementwise_max(A.v, Z.v);
    }
    if (quad == 0) {                 // untransform keys -> bf16, store row c
      uint4 e;
      e.x = (u32)unkey(A.h[0]) | ((u32)unkey(A.h[1])<<16);
      e.y = (u32)unkey(A.h[2]) | ((u32)unkey(A.h[3])<<16);
      e.z = (u32)unkey(A.h[4]) | ((u32)unkey(A.h[5])<<16);
      e.w = (u32)unkey(A.h[6]) | ((u32)unkey(A.h[7])<<16);
      *(uint4*)&sE[c*ESTRIDE + m*8] = e;
    }
  }
  __syncthreads();

  // ---- phase 3: H = E @ W^T via MFMA -> sHB[o][core] (bf16) ----
  {
    bf16x8 af[4];
    #pragma unroll
    for (int ks = 0; ks < 4; ++ks)
      af[ks] = *(const bf16x8*)&sE[m*ESTRIDE + ks*32 + quad*8];
    #pragma unroll
    for (int t = 0; t < 2; ++t) {
      int o = (wv*2 + t)*16 + m;
      f32x4 acc = {0.f, 0.f, 0.f, 0.f};
      #pragma unroll
      for (int ks = 0; ks < 4; ++ks) {
        bf16x8 bfr = *(const bf16x8*)(wt + o*NH + ks*32 + quad*8);
        acc = __builtin_amdgcn_mfma_f32_16x16x32_bf16(af[ks], bfr, acc, 0, 0, 0);
      }
      // C/D layout: col=lane&15 (o in tile), row=quad*4+reg (core)
      *(u32*)&sHB[o*HSTRIDE + quad*4]     = pack_rne(acc[0], acc[1]);
      *(u32*)&sHB[o*HSTRIDE + quad*4 + 2] = pack_rne(acc[2], acc[3]);
    }
  }
  __syncthreads();

  // ---- phase 4: out = A_norm @ H + bias (K padded 16->32) ----
  Frag afr2;
  #pragma unroll
  for (int jj = 0; jj < 4; ++jj) {
    float lo = 0.f, hi = 0.f;
    if (quad < 2) {
      int k0 = quad*8 + jj*2;
      lo = adj[m*16 + k0]     * sDinv[m] * sDinv[k0];
      hi = adj[m*16 + k0 + 1] * sDinv[m] * sDinv[k0 + 1];
    }
    afr2.u[jj] = pack_rne(lo, hi);
  }
  #pragma unroll
  for (int t = 0; t < 2; ++t) {
    int o = (wv*2 + t)*16 + m;
    float biasv = gb[(wv*2 + t)*16 + m];
    Frag bfr;
    if (quad < 2) bfr.u4 = *(const uint4*)&sHB[o*HSTRIDE + quad*8];
    else { bfr.u[0]=0; bfr.u[1]=0; bfr.u[2]=0; bfr.u[3]=0; }
    f32x4 acc = {biasv, biasv, biasv, biasv};
    acc = __builtin_amdgcn_mfma_f32_16x16x32_bf16(afr2.f, bfr.f, acc, 0, 0, 0);
    float* op = outp + b*(NC*NH) + o;
    #pragma unroll
    for (int r = 0; r < 4; ++r) op[(quad*4 + r)*NH] = acc[r];
  }
}

extern "C" void kernel_launch(void* const* d_in, const int* in_sizes, int n_in,
                              void* d_out, int out_size, void* d_ws, size_t ws_size,
                              hipStream_t stream) {
  const int*   la  = (const int*)d_in[0];    // (2048, 512) int32
  const float* adj = (const float*)d_in[1];  // (16,16) fp32
  const float* qe  = (const float*)d_in[2];  // (513,128) fp32
  const float* gw  = (const float*)d_in[3];  // (128,128) fp32
  const float* gb  = (const float*)d_in[4];  // (128,) fp32
  float* outp = (float*)d_out;               // (2048,16,128) fp32
  u16* ws = (u16*)d_ws;                      // keys (131328 B) + bf16 W (32768 B)

  int pre_threads = QE_KEYS/8 + GW_ELEMS/8;  // 10256
  prepass_kernel<<<(pre_threads + 255)/256, 256, 0, stream>>>(qe, gw, ws);
  core_snapshot_kernel<<<NB, 256, 0, stream>>>(la, adj, ws, gb, outp);
}